// Round 20
// baseline (236.592 us; speedup 1.0000x reference)
//
#include <hip/hip_runtime.h>
#include <math.h>

#define Tn 2048
#define Dn 1024
#define Hn 16
#define HDn 64

typedef float f32x4 __attribute__((ext_vector_type(4)));
typedef _Float16 f16x8 __attribute__((ext_vector_type(8)));
typedef _Float16 f16x4 __attribute__((ext_vector_type(4)));
typedef __fp16 fp16x2 __attribute__((ext_vector_type(2)));

__device__ __forceinline__ f32x4 mfma16(f16x8 a, f16x8 b, f32x4 c) {
  return __builtin_amdgcn_mfma_f32_16x16x32_f16(a, b, c, 0, 0, 0);
}

__device__ __forceinline__ void cvt_store4(_Float16* dst, float4 v) {
  union { _Float16 h[4]; uint2 u; } pk;
  pk.h[0] = (_Float16)v.x; pk.h[1] = (_Float16)v.y;
  pk.h[2] = (_Float16)v.z; pk.h[3] = (_Float16)v.w;
  *reinterpret_cast<uint2*>(dst) = pk.u;
}

__device__ __forceinline__ void nt_store4v(float* p, f32x4 t) {
  __builtin_nontemporal_store(t, reinterpret_cast<f32x4*>(p));
}

// pack 4 fp32 -> 4 fp16 via v_cvt_pkrtz (2 instrs), returned as f16x4 bits
__device__ __forceinline__ f16x4 pk4(float a, float b, float c, float d) {
  union { fp16x2 v[2]; f16x4 h; } u;
  u.v[0] = __builtin_amdgcn_cvt_pkrtz(a, b);
  u.v[1] = __builtin_amdgcn_cvt_pkrtz(c, d);
  return u.h;
}

// async global->LDS copy, 16B per lane (wave-uniform LDS base + lane*16)
__device__ __forceinline__ void gld16(const _Float16* g, _Float16* l) {
  __builtin_amdgcn_global_load_lds(
      (const __attribute__((address_space(1))) uint32_t*)g,
      (__attribute__((address_space(3))) uint32_t*)l, 16, 0, 0);
}

// soft barrier: LDS-safe workgroup barrier that does NOT drain vmcnt
#define SOFT_SYNC do {                                        \
    __builtin_amdgcn_sched_barrier(0);                        \
    asm volatile("s_waitcnt lgkmcnt(0)" ::: "memory");        \
    __builtin_amdgcn_s_barrier();                             \
    __builtin_amdgcn_sched_barrier(0);                        \
  } while (0)

// -------- one-shot fp32 -> fp16 conversion of x and all weights -------------
__global__ __launch_bounds__(256) void cvt_fp16_kernel(
    const float* __restrict__ x, const float* __restrict__ wq,
    const float* __restrict__ wk, const float* __restrict__ wv,
    const float* __restrict__ wo,
    _Float16* __restrict__ xh, _Float16* __restrict__ wqh,
    _Float16* __restrict__ wkh, _Float16* __restrict__ wvh,
    _Float16* __restrict__ woh)
{
  int i = blockIdx.x * 256 + threadIdx.x;
  const float* src; _Float16* dst; int off;
  if (i < 1048576) { src = x; dst = xh; off = i; }
  else {
    int j = i - 1048576;
    int w = j >> 18; off = j & 262143;
    src = (w == 0) ? wq : (w == 1) ? wk : (w == 2) ? wv : wo;
    dst = (w == 0) ? wqh : (w == 1) ? wkh : (w == 2) ? wvh : woh;
  }
  float4 v = reinterpret_cast<const float4*>(src)[off];
  cvt_store4(dst + (size_t)off * 4, v);
}

// -------- RoPE cos/sin tables: [T][64] fp32 ---------------------------------
__global__ void rope_table_kernel(float* __restrict__ cosT, float* __restrict__ sinT) {
  int i = blockIdx.x * 256 + threadIdx.x;
  if (i >= Tn * 32) return;
  int t = i >> 5, f = i & 31;
  float inv = powf(10000.0f, -(float)(2 * f) / 64.0f);
  float ang = (float)t * inv;
  float c = cosf(ang), s = sinf(ang);
  cosT[t * HDn + f] = c; cosT[t * HDn + f + 32] = c;
  sinT[t * HDn + f] = s; sinT[t * HDn + f + 32] = s;
}

// -------- FUSED QKV projection, 64-row m-tiles, 2 blocks/CU -----------------
// Grid 512, block 256 (4 waves). ntl = f&7 pins n-panel to XCD (W L2-hit);
// mt = f>>3 (0..63). LDS 56 KB -> 2 blocks/CU: co-resident blocks overlap
// staging drains with MFMA (the latency-hiding proj lacked at 1 block/CU).
// Wave owns 16 m-rows x 128 n-cols x 3 W: acc[3][8] f32x4.
__global__ __launch_bounds__(256) void proj_kernel(
    const _Float16* __restrict__ xh, const _Float16* __restrict__ wqh,
    const _Float16* __restrict__ wkh, const _Float16* __restrict__ wvh,
    const float* __restrict__ cosT, const float* __restrict__ sinT,
    _Float16* __restrict__ qh, _Float16* __restrict__ kh, _Float16* __restrict__ vh)
{
  __shared__ alignas(16) _Float16 As[64 * 64];
  __shared__ alignas(16) _Float16 Bs[3][128 * 64];
  const int tid = threadIdx.x;                 // 0..255
  const int lane = tid & 63, wave = tid >> 6;  // wave 0..3
  const int lrow = lane & 15, lhi = lane >> 4;
  const int f = blockIdx.x;
  const int ntl = f & 7;                       // n-panel pinned to XCD f&7
  const int mt = f >> 3;                       // 0..63
  const int m0 = mt * 64, n0 = ntl * 128;

  f32x4 acc[3][8];
#pragma unroll
  for (int w3 = 0; w3 < 3; ++w3)
#pragma unroll
    for (int nf = 0; nf < 8; ++nf) acc[w3][nf] = f32x4{0.f, 0.f, 0.f, 0.f};

  for (int k0 = 0; k0 < Dn; k0 += 64) {
    // x tile: 512 chunks (2/thread); W tiles: 1024 chunks each (4/thread)
#pragma unroll
    for (int it = 0; it < 2; ++it) {
      int n = it * 256 + tid;
      int row = n >> 3, cc = n & 7;
      int csw = cc ^ (row & 7);
      _Float16* lb = As + (size_t)(it * 256 + wave * 64) * 8;
      gld16(xh + (size_t)(m0 + row) * Dn + k0 + csw * 8, lb);
    }
#pragma unroll
    for (int it = 0; it < 4; ++it) {
      int n = it * 256 + tid;
      int row = n >> 3, cc = n & 7;
      int csw = cc ^ (row & 7);
#pragma unroll
      for (int w3 = 0; w3 < 3; ++w3) {
        _Float16* lb = Bs[w3] + (size_t)(it * 256 + wave * 64) * 8;
        gld16((w3 == 0 ? wqh : w3 == 1 ? wkh : wvh) +
                  (size_t)(n0 + row) * Dn + k0 + csw * 8, lb);
      }
    }
    __syncthreads();   // drains vmcnt -> LDS tiles complete
#pragma unroll
    for (int kc = 0; kc < 2; ++kc) {
      int arow = wave * 16 + lrow;
      f16x8 af = *reinterpret_cast<const f16x8*>(
          As + arow * 64 + (((kc * 4 + lhi) ^ (arow & 7)) << 3));
#pragma unroll
      for (int w3 = 0; w3 < 3; ++w3) {
        f16x8 bf[8];
#pragma unroll
        for (int nf = 0; nf < 8; ++nf) {
          int brow = nf * 16 + lrow;
          bf[nf] = *reinterpret_cast<const f16x8*>(
              Bs[w3] + brow * 64 + (((kc * 4 + lhi) ^ (brow & 7)) << 3));
        }
#pragma unroll
        for (int nf = 0; nf < 8; ++nf)
          acc[w3][nf] = mfma16(af, bf[nf], acc[w3][nf]);
      }
    }
    __syncthreads();
  }

  // epilogue: RoPE for q/k (partner frag nf^2; sign by nf&2), plain for v
#pragma unroll
  for (int w3 = 0; w3 < 3; ++w3) {
    _Float16* __restrict__ dst = (w3 == 0) ? qh : (w3 == 1) ? kh : vh;
    const bool isqk = (w3 < 2);
#pragma unroll
    for (int nf = 0; nf < 8; ++nf) {
#pragma unroll
      for (int r = 0; r < 4; ++r) {
        int rowg = m0 + wave * 16 + lhi * 4 + r;
        int bb = rowg >> 11, t = rowg & (Tn - 1);
        int colg = n0 + nf * 16 + lrow;
        int hh = colg >> 6, d = colg & 63;
        float val = acc[w3][nf][r];
        if (isqk) {
          float partner = acc[w3][nf ^ 2][r];
          float rot = ((nf & 2) == 0) ? -partner : partner;
          val = val * cosT[t * HDn + d] + rot * sinT[t * HDn + d];
        }
        dst[(((size_t)(bb * Hn + hh)) * Tn + t) * HDn + d] = (_Float16)val;
      }
    }
  }
}

// -------- attention: EXACT round-10 kernel (best known, attn = 134.6us) -----
__global__ __launch_bounds__(256) void attn_kernel(
    const _Float16* __restrict__ qh, const _Float16* __restrict__ kh,
    const _Float16* __restrict__ vh, float* __restrict__ attnw,
    _Float16* __restrict__ obuf)
{
  const int f = blockIdx.x;
  const int s = f >> 3, g = s >> 5;
  const int my_bh = (f & 7) + 8 * g;
  const int c = ((s & 31) + 8 * g) & 31;
  const int b = my_bh >> 4, h = my_bh & 15;
  const size_t bh = (size_t)my_bh;
  const _Float16* __restrict__ Qp = qh + bh * Tn * HDn;
  const _Float16* __restrict__ Kp = kh + bh * Tn * HDn;
  const _Float16* __restrict__ Vp = vh + bh * Tn * HDn;
  float* __restrict__ attnp = attnw + bh * (size_t)Tn * Tn;

  __shared__ _Float16 Ks[128][72];    // K tile [token][d]
  __shared__ _Float16 Vt[64][136];    // V^T [d][tok], token-blocks XOR-swizzled
  __shared__ _Float16 Pt[4][16][136]; // per-wave private P transpose [q][k]

  const int tid = threadIdx.x;
  const int lane = tid & 63, wave = tid >> 6;
  const int q16 = lane & 15, lhi = lane >> 4;
  const int qp0 = c * 64;
  const int wrow = qp0 + wave * 16;
  const int qg = wrow + q16;          // this lane's q-row
  const int ntiles = (c >> 1) + 1;

  // Q B-fragments; fold scale*log2e = 0.125*1.4426950 so S is in log2 domain
  f16x8 bq[2];
#pragma unroll
  for (int kc = 0; kc < 2; ++kc) {
    bq[kc] = *reinterpret_cast<const f16x8*>(
        Qp + (size_t)qg * HDn + kc * 32 + lhi * 8);
    bq[kc] = bq[kc] * (_Float16)0.18033688f;
  }

  // ---- pass 1: l = sum_k exp2(s) for this lane's q ----
  float lsum = 0.f;
  for (int kt = 0; kt < ntiles; ++kt) {
#pragma unroll
    for (int it = 0; it < 4; ++it) {
      int idx = it * 2048 + tid * 8;
      int r = idx >> 6, cc = idx & 63;
      *reinterpret_cast<uint4*>(&Ks[r][cc]) =
          *reinterpret_cast<const uint4*>(Kp + (size_t)(kt * 128 + r) * HDn + cc);
    }
    SOFT_SYNC;
    f32x4 st[8];
#pragma unroll
    for (int nf = 0; nf < 8; ++nf) st[nf] = f32x4{0.f, 0.f, 0.f, 0.f};
#pragma unroll
    for (int kc = 0; kc < 2; ++kc) {
      f16x8 ak[8];
#pragma unroll
      for (int nf = 0; nf < 8; ++nf)
        ak[nf] = *reinterpret_cast<const f16x8*>(&Ks[nf * 16 + q16][kc * 32 + lhi * 8]);
#pragma unroll
      for (int nf = 0; nf < 8; ++nf) st[nf] = mfma16(ak[nf], bq[kc], st[nf]);
    }
    const bool diag = (kt == ntiles - 1);
#pragma unroll
    for (int nf = 0; nf < 8; ++nf) {
      int kbase = kt * 128 + nf * 16 + lhi * 4;
#pragma unroll
      for (int r = 0; r < 4; ++r) {
        float v = st[nf][r];
        if (diag && (kbase + r) > qg) v = -INFINITY;
        lsum += __builtin_amdgcn_exp2f(v);
      }
    }
    SOFT_SYNC;
  }
  // reduce over the 4 lanes holding the same q (lhi groups)
  lsum += __shfl_xor(lsum, 16);
  lsum += __shfl_xor(lsum, 32);
  const float lg = __builtin_amdgcn_logf(lsum);   // log2(l)

  // ---- pass 2: recompute S^T, P = exp2(s - lg) -> Pt -> coalesced store + PV
  f32x4 oacc[4];
#pragma unroll
  for (int df = 0; df < 4; ++df) oacc[df] = f32x4{0.f, 0.f, 0.f, 0.f};

  for (int kt = 0; kt < ntiles; ++kt) {
#pragma unroll
    for (int it = 0; it < 4; ++it) {
      int idx = it * 2048 + tid * 8;
      int r = idx >> 6, cc = idx & 63;
      *reinterpret_cast<uint4*>(&Ks[r][cc]) =
          *reinterpret_cast<const uint4*>(Kp + (size_t)(kt * 128 + r) * HDn + cc);
      uint4 vv = *reinterpret_cast<const uint4*>(Vp + (size_t)(kt * 128 + r) * HDn + cc);
      const _Float16* pv = reinterpret_cast<const _Float16*>(&vv);
      int colb = ((((r >> 3) ^ (cc >> 3)) & 15) << 3) | (r & 7);
#pragma unroll
      for (int j = 0; j < 8; ++j) Vt[cc + j][colb] = pv[j];
    }
    SOFT_SYNC;
    f32x4 st[8];
#pragma unroll
    for (int nf = 0; nf < 8; ++nf) st[nf] = f32x4{0.f, 0.f, 0.f, 0.f};
#pragma unroll
    for (int kc = 0; kc < 2; ++kc) {
      f16x8 ak[8];
#pragma unroll
      for (int nf = 0; nf < 8; ++nf)
        ak[nf] = *reinterpret_cast<const f16x8*>(&Ks[nf * 16 + q16][kc * 32 + lhi * 8]);
#pragma unroll
      for (int nf = 0; nf < 8; ++nf) st[nf] = mfma16(ak[nf], bq[kc], st[nf]);
    }
    const bool diag = (kt == ntiles - 1);
#pragma unroll
    for (int nf = 0; nf < 8; ++nf) {
      int kbase = kt * 128 + nf * 16 + lhi * 4;
      float p[4];
#pragma unroll
      for (int r = 0; r < 4; ++r) {
        float v = st[nf][r];
        if (diag && (kbase + r) > qg) v = -INFINITY;
        p[r] = __builtin_amdgcn_exp2f(v - lg);
      }
      *reinterpret_cast<f16x4*>(&Pt[wave][q16][nf * 16 + lhi * 4]) =
          pk4(p[0], p[1], p[2], p[3]);
    }
    // PV: A = P (row=q at lane&15), B = V^T; per-wave LDS, no barrier needed
#pragma unroll
    for (int kc2 = 0; kc2 < 4; ++kc2) {
      f16x8 ap = *reinterpret_cast<const f16x8*>(&Pt[wave][q16][kc2 * 32 + lhi * 8]);
      f16x8 bv[4];
#pragma unroll
      for (int df = 0; df < 4; ++df) {
        int d = df * 16 + q16;
        int colb = (((4 * kc2 + lhi) ^ ((d >> 3) & 7)) & 15) << 3;
        bv[df] = *reinterpret_cast<const f16x8*>(&Vt[d][colb]);
      }
#pragma unroll
      for (int df = 0; df < 4; ++df) oacc[df] = mfma16(ap, bv[df], oacc[df]);
    }
    // coalesced P store: lanes 0-31 = row q(2i), lanes 32-63 = row q(2i+1)
    {
      const int qrd = (lane >> 5);
      const int k4 = (lane & 31) * 4;
#pragma unroll
      for (int it2 = 0; it2 < 8; ++it2) {
        int qrow = it2 * 2 + qrd;
        f16x4 ph = *reinterpret_cast<const f16x4*>(&Pt[wave][qrow][k4]);
        f32x4 pf;
        pf[0] = (float)ph[0]; pf[1] = (float)ph[1];
        pf[2] = (float)ph[2]; pf[3] = (float)ph[3];
        nt_store4v(attnp + (size_t)(wrow + qrow) * Tn + kt * 128 + k4, pf);
      }
    }
    SOFT_SYNC;
  }

  // O -> obuf [B*T][D] fp16 (O C-layout: col=d at lane&15, row=q at lhi*4+r)
#pragma unroll
  for (int df = 0; df < 4; ++df)
#pragma unroll
    for (int r = 0; r < 4; ++r)
      obuf[((size_t)(b * Tn + wrow + lhi * 4 + r)) * Dn + h * HDn + df * 16 + q16] =
          (_Float16)oacc[df][r];

  // zero-fill fully-masked columns (non-temporal)
  int zc0 = ntiles * 128;
  if (zc0 < Tn) {
    int n4 = (Tn - zc0) >> 2;
    int total = 64 * n4;
    for (int i = tid; i < total; i += 256) {
      int r = i / n4, cc = (i - r * n4) * 4;
      f32x4 z = f32x4{0.f, 0.f, 0.f, 0.f};
      nt_store4v(attnp + (size_t)(qp0 + r) * Tn + zc0 + cc, z);
    }
  }
}

// -------- output projection, 64-row m-tiles, grid 512, 2+ blocks/CU ---------
__global__ __launch_bounds__(256) void outproj_kernel(
    const _Float16* __restrict__ obuf, const _Float16* __restrict__ woh,
    float* __restrict__ out)
{
  __shared__ alignas(16) _Float16 As[64 * 64];
  __shared__ alignas(16) _Float16 Bs[128 * 64];
  const int tid = threadIdx.x;
  const int lane = tid & 63, wave = tid >> 6;
  const int lrow = lane & 15, lhi = lane >> 4;
  const int f = blockIdx.x;
  const int ntl = f & 7;                 // n-panel pinned to XCD
  const int mt = f >> 3;                 // 0..63
  const int m0 = mt * 64, n0 = ntl * 128;
  f32x4 acc[8];
#pragma unroll
  for (int nf = 0; nf < 8; ++nf) acc[nf] = f32x4{0.f, 0.f, 0.f, 0.f};

  for (int k0 = 0; k0 < Dn; k0 += 64) {
#pragma unroll
    for (int it = 0; it < 2; ++it) {
      int n = it * 256 + tid;
      int row = n >> 3, cc = n & 7;
      int csw = cc ^ (row & 7);
      _Float16* lb = As + (size_t)(it * 256 + wave * 64) * 8;
      gld16(obuf + (size_t)(m0 + row) * Dn + k0 + csw * 8, lb);
    }
#pragma unroll
    for (int it = 0; it < 4; ++it) {
      int n = it * 256 + tid;
      int row = n >> 3, cc = n & 7;
      int csw = cc ^ (row & 7);
      _Float16* lb = Bs + (size_t)(it * 256 + wave * 64) * 8;
      gld16(woh + (size_t)(n0 + row) * Dn + k0 + csw * 8, lb);
    }
    __syncthreads();
#pragma unroll
    for (int kc = 0; kc < 2; ++kc) {
      int arow = wave * 16 + lrow;
      f16x8 af = *reinterpret_cast<const f16x8*>(
          As + arow * 64 + (((kc * 4 + lhi) ^ (arow & 7)) << 3));
      f16x8 bf[8];
#pragma unroll
      for (int nf = 0; nf < 8; ++nf) {
        int brow = nf * 16 + lrow;
        bf[nf] = *reinterpret_cast<const f16x8*>(
            Bs + brow * 64 + (((kc * 4 + lhi) ^ (brow & 7)) << 3));
      }
#pragma unroll
      for (int nf = 0; nf < 8; ++nf) acc[nf] = mfma16(af, bf[nf], acc[nf]);
    }
    __syncthreads();
  }
#pragma unroll
  for (int nf = 0; nf < 8; ++nf)
#pragma unroll
    for (int r = 0; r < 4; ++r) {
      int rowg = m0 + wave * 16 + lhi * 4 + r;
      int colg = n0 + nf * 16 + lrow;
      out[(size_t)rowg * Dn + colg] = acc[nf][r];
    }
}

extern "C" void kernel_launch(void* const* d_in, const int* in_sizes, int n_in,
                              void* d_out, int out_size, void* d_ws, size_t ws_size,
                              hipStream_t stream) {
  const float* x  = (const float*)d_in[0];
  const float* Wq = (const float*)d_in[2];
  const float* Wk = (const float*)d_in[3];
  const float* Wv = (const float*)d_in[4];
  const float* Wo = (const float*)d_in[5];

  float* out   = (float*)d_out;                      // [2,2048,1024]
  float* attnw = out + (size_t)2 * Tn * Dn;          // [2,16,2048,2048]

  // workspace layout (~43 MB): tables | xh(alias obuf) | 4x W fp16 | q/k/v fp16
  char* ws = (char*)d_ws;
  float* cosT = (float*)ws;
  float* sinT = cosT + Tn * HDn;
  _Float16* xh   = (_Float16*)(sinT + Tn * HDn);
  _Float16* obuf = xh;                               // xh dead after proj
  _Float16* wqh  = xh + (size_t)2 * Tn * Dn;
  _Float16* wkh  = wqh + Dn * Dn;
  _Float16* wvh  = wkh + Dn * Dn;
  _Float16* woh  = wvh + Dn * Dn;
  _Float16* qh   = woh + Dn * Dn;
  _Float16* kh   = qh + (size_t)2 * Tn * Dn;
  _Float16* vh   = kh + (size_t)2 * Tn * Dn;

  cvt_fp16_kernel<<<dim3(8192), 256, 0, stream>>>(x, Wq, Wk, Wv, Wo,
                                                  xh, wqh, wkh, wvh, woh);
  rope_table_kernel<<<dim3(256), 256, 0, stream>>>(cosT, sinT);
  proj_kernel<<<dim3(512), 256, 0, stream>>>(xh, wqh, wkh, wvh,
                                             cosT, sinT, qh, kh, vh);
  attn_kernel<<<dim3(1024), 256, 0, stream>>>(qh, kh, vh, attnw, obuf);
  outproj_kernel<<<dim3(512), 256, 0, stream>>>(obuf, woh, out);
}

// Round 21
// 214.228 us; speedup vs baseline: 1.1044x; 1.1044x over previous
//
#include <hip/hip_runtime.h>
#include <math.h>

#define Tn 2048
#define Dn 1024
#define Hn 16
#define HDn 64

typedef float f32x4 __attribute__((ext_vector_type(4)));
typedef _Float16 f16x8 __attribute__((ext_vector_type(8)));
typedef _Float16 f16x4 __attribute__((ext_vector_type(4)));
typedef __fp16 fp16x2 __attribute__((ext_vector_type(2)));

__device__ __forceinline__ f32x4 mfma16(f16x8 a, f16x8 b, f32x4 c) {
  return __builtin_amdgcn_mfma_f32_16x16x32_f16(a, b, c, 0, 0, 0);
}

__device__ __forceinline__ void cvt_store4(_Float16* dst, float4 v) {
  union { _Float16 h[4]; uint2 u; } pk;
  pk.h[0] = (_Float16)v.x; pk.h[1] = (_Float16)v.y;
  pk.h[2] = (_Float16)v.z; pk.h[3] = (_Float16)v.w;
  *reinterpret_cast<uint2*>(dst) = pk.u;
}

__device__ __forceinline__ void nt_store4v(float* p, f32x4 t) {
  __builtin_nontemporal_store(t, reinterpret_cast<f32x4*>(p));
}

// pack 4 fp32 -> 4 fp16 via v_cvt_pkrtz (2 instrs), returned as f16x4 bits
__device__ __forceinline__ f16x4 pk4(float a, float b, float c, float d) {
  union { fp16x2 v[2]; f16x4 h; } u;
  u.v[0] = __builtin_amdgcn_cvt_pkrtz(a, b);
  u.v[1] = __builtin_amdgcn_cvt_pkrtz(c, d);
  return u.h;
}

// async global->LDS copy, 16B per lane (wave-uniform LDS base + lane*16)
__device__ __forceinline__ void gld16(const _Float16* g, _Float16* l) {
  __builtin_amdgcn_global_load_lds(
      (const __attribute__((address_space(1))) uint32_t*)g,
      (__attribute__((address_space(3))) uint32_t*)l, 16, 0, 0);
}

// soft barrier: LDS-safe workgroup barrier that does NOT drain vmcnt
#define SOFT_SYNC do {                                        \
    __builtin_amdgcn_sched_barrier(0);                        \
    asm volatile("s_waitcnt lgkmcnt(0)" ::: "memory");        \
    __builtin_amdgcn_s_barrier();                             \
    __builtin_amdgcn_sched_barrier(0);                        \
  } while (0)

// -------- fp32->fp16 conversion of x/weights + RoPE tables, one launch ------
// blocks 0..8191: convert (float4 granularity); blocks 8192..8447: rope table.
__global__ __launch_bounds__(256) void cvt_rope_kernel(
    const float* __restrict__ x, const float* __restrict__ wq,
    const float* __restrict__ wk, const float* __restrict__ wv,
    const float* __restrict__ wo,
    _Float16* __restrict__ xh, _Float16* __restrict__ wqh,
    _Float16* __restrict__ wkh, _Float16* __restrict__ wvh,
    _Float16* __restrict__ woh,
    float* __restrict__ cosT, float* __restrict__ sinT)
{
  int i = blockIdx.x * 256 + threadIdx.x;
  if (i < 2097152) {
    const float* src; _Float16* dst; int off;
    if (i < 1048576) { src = x; dst = xh; off = i; }
    else {
      int j = i - 1048576;
      int w = j >> 18; off = j & 262143;
      src = (w == 0) ? wq : (w == 1) ? wk : (w == 2) ? wv : wo;
      dst = (w == 0) ? wqh : (w == 1) ? wkh : (w == 2) ? wvh : woh;
    }
    float4 v = reinterpret_cast<const float4*>(src)[off];
    cvt_store4(dst + (size_t)off * 4, v);
  } else {
    int i2 = i - 2097152;              // 0..65535 = Tn*32
    int t = i2 >> 5, f2 = i2 & 31;
    float inv = powf(10000.0f, -(float)(2 * f2) / 64.0f);
    float ang = (float)t * inv;
    float c = cosf(ang), s = sinf(ang);
    cosT[t * HDn + f2] = c; cosT[t * HDn + f2 + 32] = c;
    sinT[t * HDn + f2] = s; sinT[t * HDn + f2 + 32] = s;
  }
}

// -------- FUSED QKV projection: q,k,v = x @ {Wq,Wk,Wv}^T, RoPE on q/k -------
// Grid 256, block 512 (8 waves). ntl = blockIdx&7 pins each n-panel to one
// XCD: per-XCD W working set = 3 x 128-col panel x K=1024 fp16 = 768 KB,
// L2-resident -> W re-reads are L2 hits. x-tile staged ONCE for 3x MFMA.
__global__ __launch_bounds__(512) void proj_kernel(
    const _Float16* __restrict__ xh, const _Float16* __restrict__ wqh,
    const _Float16* __restrict__ wkh, const _Float16* __restrict__ wvh,
    const float* __restrict__ cosT, const float* __restrict__ sinT,
    _Float16* __restrict__ qh, _Float16* __restrict__ kh, _Float16* __restrict__ vh)
{
  __shared__ alignas(16) _Float16 As[128 * 64];
  __shared__ alignas(16) _Float16 Bs[3][128 * 64];
  const int tid = threadIdx.x;                 // 0..511
  const int lane = tid & 63, wave = tid >> 6;  // wave 0..7
  const int lrow = lane & 15, lhi = lane >> 4;
  const int f = blockIdx.x;
  const int ntl = f & 7;                       // n-panel pinned to XCD f&7
  const int mt = f >> 3;                       // 0..31
  const int m0 = mt * 128, n0 = ntl * 128;

  f32x4 acc[3][8];
#pragma unroll
  for (int w3 = 0; w3 < 3; ++w3)
#pragma unroll
    for (int nf = 0; nf < 8; ++nf) acc[w3][nf] = f32x4{0.f, 0.f, 0.f, 0.f};

  for (int k0 = 0; k0 < Dn; k0 += 64) {
    // stage x + 3 W tiles: 1024 chunks/tile, 2 chunks/thread, pre-swizzled src
#pragma unroll
    for (int it = 0; it < 2; ++it) {
      int n = it * 512 + tid;                  // chunk index 0..1023
      int row = n >> 3, cc = n & 7;
      int csw = cc ^ (row & 7);                // inverse-swizzled source chunk
      _Float16* lb = As + (size_t)(it * 512 + wave * 64) * 8;  // wave-uniform
      gld16(xh + (size_t)(m0 + row) * Dn + k0 + csw * 8, lb);
      {
        _Float16* lb2 = Bs[0] + (size_t)(it * 512 + wave * 64) * 8;
        gld16(wqh + (size_t)(n0 + row) * Dn + k0 + csw * 8, lb2);
      }
      {
        _Float16* lb2 = Bs[1] + (size_t)(it * 512 + wave * 64) * 8;
        gld16(wkh + (size_t)(n0 + row) * Dn + k0 + csw * 8, lb2);
      }
      {
        _Float16* lb2 = Bs[2] + (size_t)(it * 512 + wave * 64) * 8;
        gld16(wvh + (size_t)(n0 + row) * Dn + k0 + csw * 8, lb2);
      }
    }
    __syncthreads();   // drains vmcnt -> LDS tiles complete
#pragma unroll
    for (int kc = 0; kc < 2; ++kc) {
      int arow = wave * 16 + lrow;
      f16x8 af = *reinterpret_cast<const f16x8*>(
          As + arow * 64 + (((kc * 4 + lhi) ^ (arow & 7)) << 3));
#pragma unroll
      for (int w3 = 0; w3 < 3; ++w3) {
        f16x8 bf[8];
#pragma unroll
        for (int nf = 0; nf < 8; ++nf) {
          int brow = nf * 16 + lrow;
          bf[nf] = *reinterpret_cast<const f16x8*>(
              Bs[w3] + brow * 64 + (((kc * 4 + lhi) ^ (brow & 7)) << 3));
        }
#pragma unroll
        for (int nf = 0; nf < 8; ++nf)
          acc[w3][nf] = mfma16(af, bf[nf], acc[w3][nf]);
      }
    }
    __syncthreads();
  }

  // epilogue: RoPE for q/k (partner frag nf^2; sign by nf&2), plain for v
#pragma unroll
  for (int w3 = 0; w3 < 3; ++w3) {
    _Float16* __restrict__ dst = (w3 == 0) ? qh : (w3 == 1) ? kh : vh;
    const bool isqk = (w3 < 2);
#pragma unroll
    for (int nf = 0; nf < 8; ++nf) {
#pragma unroll
      for (int r = 0; r < 4; ++r) {
        int rowg = m0 + wave * 16 + lhi * 4 + r;
        int bb = rowg >> 11, t = rowg & (Tn - 1);
        int colg = n0 + nf * 16 + lrow;
        int hh = colg >> 6, d = colg & 63;
        float val = acc[w3][nf][r];
        if (isqk) {
          float partner = acc[w3][nf ^ 2][r];
          float rot = ((nf & 2) == 0) ? -partner : partner;
          val = val * cosT[t * HDn + d] + rot * sinT[t * HDn + d];
        }
        dst[(((size_t)(bb * Hn + hh)) * Tn + t) * HDn + d] = (_Float16)val;
      }
    }
  }
}

// -------- attention: EXACT round-10 kernel (best known, attn = 134.6us) -----
__global__ __launch_bounds__(256) void attn_kernel(
    const _Float16* __restrict__ qh, const _Float16* __restrict__ kh,
    const _Float16* __restrict__ vh, float* __restrict__ attnw,
    _Float16* __restrict__ obuf)
{
  const int f = blockIdx.x;
  const int s = f >> 3, g = s >> 5;
  const int my_bh = (f & 7) + 8 * g;
  const int c = ((s & 31) + 8 * g) & 31;
  const int b = my_bh >> 4, h = my_bh & 15;
  const size_t bh = (size_t)my_bh;
  const _Float16* __restrict__ Qp = qh + bh * Tn * HDn;
  const _Float16* __restrict__ Kp = kh + bh * Tn * HDn;
  const _Float16* __restrict__ Vp = vh + bh * Tn * HDn;
  float* __restrict__ attnp = attnw + bh * (size_t)Tn * Tn;

  __shared__ _Float16 Ks[128][72];    // K tile [token][d]
  __shared__ _Float16 Vt[64][136];    // V^T [d][tok], token-blocks XOR-swizzled
  __shared__ _Float16 Pt[4][16][136]; // per-wave private P transpose [q][k]

  const int tid = threadIdx.x;
  const int lane = tid & 63, wave = tid >> 6;
  const int q16 = lane & 15, lhi = lane >> 4;
  const int qp0 = c * 64;
  const int wrow = qp0 + wave * 16;
  const int qg = wrow + q16;          // this lane's q-row
  const int ntiles = (c >> 1) + 1;

  // Q B-fragments; fold scale*log2e = 0.125*1.4426950 so S is in log2 domain
  f16x8 bq[2];
#pragma unroll
  for (int kc = 0; kc < 2; ++kc) {
    bq[kc] = *reinterpret_cast<const f16x8*>(
        Qp + (size_t)qg * HDn + kc * 32 + lhi * 8);
    bq[kc] = bq[kc] * (_Float16)0.18033688f;
  }

  // ---- pass 1: l = sum_k exp2(s) for this lane's q ----
  float lsum = 0.f;
  for (int kt = 0; kt < ntiles; ++kt) {
#pragma unroll
    for (int it = 0; it < 4; ++it) {
      int idx = it * 2048 + tid * 8;
      int r = idx >> 6, cc = idx & 63;
      *reinterpret_cast<uint4*>(&Ks[r][cc]) =
          *reinterpret_cast<const uint4*>(Kp + (size_t)(kt * 128 + r) * HDn + cc);
    }
    SOFT_SYNC;
    f32x4 st[8];
#pragma unroll
    for (int nf = 0; nf < 8; ++nf) st[nf] = f32x4{0.f, 0.f, 0.f, 0.f};
#pragma unroll
    for (int kc = 0; kc < 2; ++kc) {
      f16x8 ak[8];
#pragma unroll
      for (int nf = 0; nf < 8; ++nf)
        ak[nf] = *reinterpret_cast<const f16x8*>(&Ks[nf * 16 + q16][kc * 32 + lhi * 8]);
#pragma unroll
      for (int nf = 0; nf < 8; ++nf) st[nf] = mfma16(ak[nf], bq[kc], st[nf]);
    }
    const bool diag = (kt == ntiles - 1);
#pragma unroll
    for (int nf = 0; nf < 8; ++nf) {
      int kbase = kt * 128 + nf * 16 + lhi * 4;
#pragma unroll
      for (int r = 0; r < 4; ++r) {
        float v = st[nf][r];
        if (diag && (kbase + r) > qg) v = -INFINITY;
        lsum += __builtin_amdgcn_exp2f(v);
      }
    }
    SOFT_SYNC;
  }
  // reduce over the 4 lanes holding the same q (lhi groups)
  lsum += __shfl_xor(lsum, 16);
  lsum += __shfl_xor(lsum, 32);
  const float lg = __builtin_amdgcn_logf(lsum);   // log2(l)

  // ---- pass 2: recompute S^T, P = exp2(s - lg) -> Pt -> coalesced store + PV
  f32x4 oacc[4];
#pragma unroll
  for (int df = 0; df < 4; ++df) oacc[df] = f32x4{0.f, 0.f, 0.f, 0.f};

  for (int kt = 0; kt < ntiles; ++kt) {
#pragma unroll
    for (int it = 0; it < 4; ++it) {
      int idx = it * 2048 + tid * 8;
      int r = idx >> 6, cc = idx & 63;
      *reinterpret_cast<uint4*>(&Ks[r][cc]) =
          *reinterpret_cast<const uint4*>(Kp + (size_t)(kt * 128 + r) * HDn + cc);
      uint4 vv = *reinterpret_cast<const uint4*>(Vp + (size_t)(kt * 128 + r) * HDn + cc);
      const _Float16* pv = reinterpret_cast<const _Float16*>(&vv);
      int colb = ((((r >> 3) ^ (cc >> 3)) & 15) << 3) | (r & 7);
#pragma unroll
      for (int j = 0; j < 8; ++j) Vt[cc + j][colb] = pv[j];
    }
    SOFT_SYNC;
    f32x4 st[8];
#pragma unroll
    for (int nf = 0; nf < 8; ++nf) st[nf] = f32x4{0.f, 0.f, 0.f, 0.f};
#pragma unroll
    for (int kc = 0; kc < 2; ++kc) {
      f16x8 ak[8];
#pragma unroll
      for (int nf = 0; nf < 8; ++nf)
        ak[nf] = *reinterpret_cast<const f16x8*>(&Ks[nf * 16 + q16][kc * 32 + lhi * 8]);
#pragma unroll
      for (int nf = 0; nf < 8; ++nf) st[nf] = mfma16(ak[nf], bq[kc], st[nf]);
    }
    const bool diag = (kt == ntiles - 1);
#pragma unroll
    for (int nf = 0; nf < 8; ++nf) {
      int kbase = kt * 128 + nf * 16 + lhi * 4;
      float p[4];
#pragma unroll
      for (int r = 0; r < 4; ++r) {
        float v = st[nf][r];
        if (diag && (kbase + r) > qg) v = -INFINITY;
        p[r] = __builtin_amdgcn_exp2f(v - lg);
      }
      *reinterpret_cast<f16x4*>(&Pt[wave][q16][nf * 16 + lhi * 4]) =
          pk4(p[0], p[1], p[2], p[3]);
    }
    // PV: A = P (row=q at lane&15), B = V^T; per-wave LDS, no barrier needed
#pragma unroll
    for (int kc2 = 0; kc2 < 4; ++kc2) {
      f16x8 ap = *reinterpret_cast<const f16x8*>(&Pt[wave][q16][kc2 * 32 + lhi * 8]);
      f16x8 bv[4];
#pragma unroll
      for (int df = 0; df < 4; ++df) {
        int d = df * 16 + q16;
        int colb = (((4 * kc2 + lhi) ^ ((d >> 3) & 7)) & 15) << 3;
        bv[df] = *reinterpret_cast<const f16x8*>(&Vt[d][colb]);
      }
#pragma unroll
      for (int df = 0; df < 4; ++df) oacc[df] = mfma16(ap, bv[df], oacc[df]);
    }
    // coalesced P store: lanes 0-31 = row q(2i), lanes 32-63 = row q(2i+1)
    {
      const int qrd = (lane >> 5);
      const int k4 = (lane & 31) * 4;
#pragma unroll
      for (int it2 = 0; it2 < 8; ++it2) {
        int qrow = it2 * 2 + qrd;
        f16x4 ph = *reinterpret_cast<const f16x4*>(&Pt[wave][qrow][k4]);
        f32x4 pf;
        pf[0] = (float)ph[0]; pf[1] = (float)ph[1];
        pf[2] = (float)ph[2]; pf[3] = (float)ph[3];
        nt_store4v(attnp + (size_t)(wrow + qrow) * Tn + kt * 128 + k4, pf);
      }
    }
    SOFT_SYNC;
  }

  // O -> obuf [B*T][D] fp16 (O C-layout: col=d at lane&15, row=q at lhi*4+r)
#pragma unroll
  for (int df = 0; df < 4; ++df)
#pragma unroll
    for (int r = 0; r < 4; ++r)
      obuf[((size_t)(b * Tn + wrow + lhi * 4 + r)) * Dn + h * HDn + df * 16 + q16] =
          (_Float16)oacc[df][r];

  // zero-fill fully-masked columns (non-temporal)
  int zc0 = ntiles * 128;
  if (zc0 < Tn) {
    int n4 = (Tn - zc0) >> 2;
    int total = 64 * n4;
    for (int i = tid; i < total; i += 256) {
      int r = i / n4, cc = (i - r * n4) * 4;
      f32x4 z = f32x4{0.f, 0.f, 0.f, 0.f};
      nt_store4v(attnp + (size_t)(qp0 + r) * Tn + zc0 + cc, z);
    }
  }
}

// -------- output projection: out = O @ Wo^T (fp16 in, fp32 out) -------------
__global__ __launch_bounds__(256) void outproj_kernel(
    const _Float16* __restrict__ obuf, const _Float16* __restrict__ woh,
    float* __restrict__ out)
{
  __shared__ alignas(16) _Float16 As[128 * 64];
  __shared__ alignas(16) _Float16 Bs[128 * 64];
  const int tid = threadIdx.x;
  const int lane = tid & 63, wave = tid >> 6;
  const int lrow = lane & 15, lhi = lane >> 4;
  const int wm = wave >> 1, wn = wave & 1;
  const int f = blockIdx.x, s = f >> 3;
  const int mt = (f & 7) + 8 * (s & 3);
  const int ntl = s >> 2;
  const int m0 = mt * 128, n0 = ntl * 128;
  f32x4 acc[4][4];
#pragma unroll
  for (int i = 0; i < 4; ++i)
#pragma unroll
    for (int j = 0; j < 4; ++j) acc[i][j] = f32x4{0.f, 0.f, 0.f, 0.f};

  for (int k0 = 0; k0 < Dn; k0 += 64) {
#pragma unroll
    for (int it = 0; it < 4; ++it) {
      int n = it * 256 + tid;
      int row = n >> 3, cc = n & 7;
      int csw = cc ^ (row & 7);
      _Float16* lbase = As + (size_t)(it * 256 + wave * 64) * 8;
      gld16(obuf + (size_t)(m0 + row) * Dn + k0 + csw * 8, lbase);
      _Float16* lbase2 = Bs + (size_t)(it * 256 + wave * 64) * 8;
      gld16(woh + (size_t)(n0 + row) * Dn + k0 + csw * 8, lbase2);
    }
    __syncthreads();
#pragma unroll
    for (int kc = 0; kc < 2; ++kc) {
      f16x8 af[4], bf[4];
#pragma unroll
      for (int i = 0; i < 4; ++i) {
        int row = wm * 64 + i * 16 + lrow;
        af[i] = *reinterpret_cast<const f16x8*>(
            As + row * 64 + (((kc * 4 + lhi) ^ (row & 7)) << 3));
      }
#pragma unroll
      for (int j = 0; j < 4; ++j) {
        int row = wn * 64 + j * 16 + lrow;
        bf[j] = *reinterpret_cast<const f16x8*>(
            Bs + row * 64 + (((kc * 4 + lhi) ^ (row & 7)) << 3));
      }
#pragma unroll
      for (int i = 0; i < 4; ++i)
#pragma unroll
        for (int j = 0; j < 4; ++j)
          acc[i][j] = mfma16(af[i], bf[j], acc[i][j]);
    }
    __syncthreads();
  }
#pragma unroll
  for (int i = 0; i < 4; ++i)
#pragma unroll
    for (int j = 0; j < 4; ++j)
#pragma unroll
      for (int r = 0; r < 4; ++r) {
        int rowg = m0 + wm * 64 + i * 16 + lhi * 4 + r;
        int colg = n0 + wn * 64 + j * 16 + lrow;
        out[(size_t)rowg * Dn + colg] = acc[i][j][r];
      }
}

extern "C" void kernel_launch(void* const* d_in, const int* in_sizes, int n_in,
                              void* d_out, int out_size, void* d_ws, size_t ws_size,
                              hipStream_t stream) {
  const float* x  = (const float*)d_in[0];
  const float* Wq = (const float*)d_in[2];
  const float* Wk = (const float*)d_in[3];
  const float* Wv = (const float*)d_in[4];
  const float* Wo = (const float*)d_in[5];

  float* out   = (float*)d_out;                      // [2,2048,1024]
  float* attnw = out + (size_t)2 * Tn * Dn;          // [2,16,2048,2048]

  // workspace layout (~43 MB): tables | xh(alias obuf) | 4x W fp16 | q/k/v fp16
  char* ws = (char*)d_ws;
  float* cosT = (float*)ws;
  float* sinT = cosT + Tn * HDn;
  _Float16* xh   = (_Float16*)(sinT + Tn * HDn);
  _Float16* obuf = xh;                               // xh dead after proj
  _Float16* wqh  = xh + (size_t)2 * Tn * Dn;
  _Float16* wkh  = wqh + Dn * Dn;
  _Float16* wvh  = wkh + Dn * Dn;
  _Float16* woh  = wvh + Dn * Dn;
  _Float16* qh   = woh + Dn * Dn;
  _Float16* kh   = qh + (size_t)2 * Tn * Dn;
  _Float16* vh   = kh + (size_t)2 * Tn * Dn;

  cvt_rope_kernel<<<dim3(8448), 256, 0, stream>>>(x, Wq, Wk, Wv, Wo,
                                                  xh, wqh, wkh, wvh, woh,
                                                  cosT, sinT);
  proj_kernel<<<dim3(256), 512, 0, stream>>>(xh, wqh, wkh, wvh,
                                             cosT, sinT, qh, kh, vh);
  attn_kernel<<<dim3(1024), 256, 0, stream>>>(qh, kh, vh, attnw, obuf);
  outproj_kernel<<<dim3(256), 256, 0, stream>>>(obuf, woh, out);
}